// Round 3
// baseline (533.694 us; speedup 1.0000x reference)
//
#include <hip/hip_runtime.h>
#include <hip/hip_bf16.h>
#include <math.h>

#define Bn 8
#define Cn 1152
#define Nn 1024  // H*W
#define GRID 1152

typedef short short8 __attribute__((ext_vector_type(8)));
typedef float f32x4 __attribute__((ext_vector_type(4)));

// Intermediates. Fully overwritten every call (poison-safe).
__device__ float g_csp[Bn * 128 * Nn];  // per-(b, 8-row group) partial column sums (4 MB)
__device__ float g_ics[Bn * Nn];        // 1/colsum
__device__ unsigned short g_A[(size_t)Bn * Nn * Nn];  // E[b][i][j] bf16 (unnormalized)

// Software grid barrier (sense via generation counter). Works across harness
// iterations since count returns to 0 and gen monotonically increases.
__device__ unsigned g_bar_count = 0;
__device__ unsigned g_bar_gen = 0;

__device__ inline void grid_barrier() {
    __syncthreads();
    if (threadIdx.x == 0) {
        __threadfence();  // block's prior global stores -> visible at agent scope
        unsigned gen = __hip_atomic_load(&g_bar_gen, __ATOMIC_ACQUIRE, __HIP_MEMORY_SCOPE_AGENT);
        unsigned arr =
            __hip_atomic_fetch_add(&g_bar_count, 1u, __ATOMIC_ACQ_REL, __HIP_MEMORY_SCOPE_AGENT);
        if (arr + 1u == (unsigned)GRID) {
            __hip_atomic_store(&g_bar_count, 0u, __ATOMIC_RELAXED, __HIP_MEMORY_SCOPE_AGENT);
            __hip_atomic_fetch_add(&g_bar_gen, 1u, __ATOMIC_RELEASE, __HIP_MEMORY_SCOPE_AGENT);
        } else {
            while (__hip_atomic_load(&g_bar_gen, __ATOMIC_ACQUIRE, __HIP_MEMORY_SCOPE_AGENT) ==
                   gen)
                __builtin_amdgcn_s_sleep(1);
        }
    }
    __syncthreads();
}

__device__ inline unsigned short f2bf(float x) {
    __hip_bfloat16 h = __float2bfloat16(x);
    unsigned short u;
    __builtin_memcpy(&u, &h, 2);
    return u;
}

__device__ inline void inv3(const float* M, float* o) {
    float a = M[0], b = M[1], c = M[2];
    float d = M[3], e = M[4], f = M[5];
    float g = M[6], h = M[7], i = M[8];
    float A0 = (e * i - f * h);
    float A1 = -(d * i - f * g);
    float A2 = (d * h - e * g);
    float det = a * A0 + b * A1 + c * A2;
    float inv = 1.0f / det;
    o[0] = A0 * inv;
    o[1] = -(b * i - c * h) * inv;
    o[2] = (b * f - c * e) * inv;
    o[3] = A1 * inv;
    o[4] = (a * i - c * g) * inv;
    o[5] = -(a * f - c * d) * inv;
    o[6] = A2 * inv;
    o[7] = -(a * h - b * g) * inv;
    o[8] = (a * e - b * d) * inv;
}

__device__ inline void mm3(const float* X, const float* Y, float* Z) {
    for (int r = 0; r < 3; r++)
        for (int c = 0; c < 3; c++)
            Z[r * 3 + c] = X[r * 3 + 0] * Y[0 * 3 + c] + X[r * 3 + 1] * Y[1 * 3 + c] +
                           X[r * 3 + 2] * Y[2 * 3 + c];
}

// F = inv(K2^T) skew(t) R inv(K1). SVD in the reference is a rank-2 no-op.
__device__ inline void computeF(const float* K1, const float* K2, const float* R,
                                const float* t, int b, float* F) {
    float t0 = t[b * 3 + 0], t1 = t[b * 3 + 1], t2 = t[b * 3 + 2];
    float S[9] = {0.0f, -t2, t1, t2, 0.0f, -t0, -t1, t0, 0.0f};
    float E[9];
    mm3(S, &R[b * 9], E);
    float iK1[9], iK2[9];
    inv3(&K1[b * 9], iK1);
    inv3(&K2[b * 9], iK2);
    float iK2T[9] = {iK2[0], iK2[3], iK2[6], iK2[1], iK2[4], iK2[7], iK2[2], iK2[5], iK2[8]};
    float T[9];
    mm3(iK2T, E, T);
    mm3(T, iK1, F);
}

// Per-j coefficients: z_ij = |ix*P + iy*Q - R| - 0.5  (== 5*(d_epi - 0.1))
__device__ inline float4 zcoef(const float* F, int j) {
    float jx = (float)(j >> 5);
    float jy = (float)(j & 31);
    float l0 = F[0] * jx + F[1] * jy + F[2];
    float l1 = F[3] * jx + F[4] * jy + F[5];
    float l2 = F[6] * jx + F[7] * jy + F[8];
    l0 = l0 / l2;
    l1 = l1 / l2;
    float y0 = -1.0f / l1;
    float y1 = -(1.0f + l0 * 32.0f) / l1;
    float dy = y0 - y1;
    float invn = 1.0f / sqrtf(1024.0f + dy * dy);
    return make_float4(5.0f * dy * invn, 160.0f * invn, 160.0f * y0 * invn, 0.0f);
}

#define BM 128
#define BNc 64
#define BK 32

// Single fused kernel: P1 E+partial csums -> barrier -> P2 1/colsum -> barrier
// -> P3 GEMM with T14 split-staged B (fused 1/csum scale + bf16 convert).
// LDS 28 KB, 256 threads, launch_bounds(256,5): 5 blocks/CU * 256 CU = 1280 >=
// 1152 blocks -> all blocks co-resident -> software barrier is safe.
__launch_bounds__(256, 5) __global__ void mega_kernel(
    const float* __restrict__ K1, const float* __restrict__ K2, const float* __restrict__ R,
    const float* __restrict__ t, const float* __restrict__ fsrc, float* __restrict__ out) {
    __shared__ __align__(16) char smem[28672];
    int lin = blockIdx.x;
    int tid = threadIdx.x;
    int b = lin & 7;  // XCD heuristic; correctness barrier-enforced

    // ---------------- P1: E = exp(1 - rowsoftmax) + 8-row column partials ----
    if (lin < 1024) {
        float* prmx = (float*)smem;             // 4 KB
        float* prmy = (float*)(smem + 4096);    // 4 KB
        float* prmz = (float*)(smem + 8192);    // 4 KB
        float* Fs = (float*)(smem + 12288);     // aliases red (used before it)
        float(*red)[16][64] = (float(*)[16][64])(smem + 12288);  // 16 KB
        int seg = lin >> 3;  // 0..127, 8 rows per block
        if (tid == 0) computeF(K1, K2, R, t, b, Fs);
        __syncthreads();
#pragma unroll
        for (int u = 0; u < 4; u++) {
            int j = tid * 4 + u;
            float4 p = zcoef(Fs, j);
            prmx[j] = p.x;
            prmy[j] = p.y;
            prmz[j] = p.z;
        }
        __syncthreads();
        int wv = tid >> 6, lane = tid & 63;
#pragma unroll
        for (int rr = 0; rr < 2; rr++) {
            int i = seg * 8 + wv * 2 + rr;
            float ix = (float)(i >> 5), iy = (float)(i & 31);
            float e[16], m = -INFINITY;
#pragma unroll
            for (int k = 0; k < 16; k++) {
                int j = lane + k * 64;
                e[k] = fabsf(fmaf(ix, prmx[j], fmaf(iy, prmy[j], -prmz[j]))) - 0.5f;
                m = fmaxf(m, e[k]);
            }
#pragma unroll
            for (int o = 32; o > 0; o >>= 1) m = fmaxf(m, __shfl_xor(m, o, 64));
            float s = 0.0f;
#pragma unroll
            for (int k = 0; k < 16; k++) {
                e[k] = __expf(e[k] - m);
                s += e[k];
            }
#pragma unroll
            for (int o = 32; o > 0; o >>= 1) s += __shfl_xor(s, o, 64);
            float rsi = 1.0f / s;
            unsigned short* arow = g_A + (size_t)(b * Nn + i) * Nn;
#pragma unroll
            for (int k = 0; k < 16; k++) {
                float E = __expf(1.0f - e[k] * rsi);
                arow[lane + k * 64] = f2bf(E);
                if (rr == 0)
                    red[wv][k][lane] = E;
                else
                    red[wv][k][lane] += E;
            }
        }
        __syncthreads();
        int l2 = tid & 63, k0 = (tid >> 6) * 4;
#pragma unroll
        for (int q = 0; q < 4; q++) {
            int k = k0 + q;
            float ssum = red[0][k][l2] + red[1][k][l2] + red[2][k][l2] + red[3][k][l2];
            g_csp[((size_t)(b * 128 + seg)) * Nn + k * 64 + l2] = ssum;
        }
    }
    grid_barrier();

    // ---------------- P2: 1/colsum over 128 partials, 256 blocks -------------
    if (lin < 256) {
        float* red2 = (float*)smem;  // 256 floats
        int jl = tid & 31, sg = tid >> 5;  // 8 s-groups of 16
        int jbase = (lin >> 3) * 32;
        const float* base = g_csp + (size_t)b * 128 * Nn + jbase + jl;
        float sum = 0.0f;
#pragma unroll
        for (int u = 0; u < 16; u++) sum += base[(size_t)(sg * 16 + u) * Nn];
        red2[tid] = sum;
        __syncthreads();
        if (tid < 32) {
            float ssum = red2[tid];
#pragma unroll
            for (int g2 = 1; g2 < 8; g2++) ssum += red2[g2 * 32 + tid];
            g_ics[b * Nn + jbase + tid] = 1.0f / ssum;
        }
    }
    grid_barrier();

    // ---------------- P3: out = E * (f_src/csum)^T GEMM ----------------------
    {
        unsigned short* As0 = (unsigned short*)smem;           // 2 x 8 KB
        unsigned short* Bs0 = (unsigned short*)(smem + 16384); // 2 x 4 KB
        float* ics = (float*)(smem + 24576);                   // 4 KB
        int sblk = lin >> 3;       // 0..143
        int it = sblk & 7;
        int ct = sblk >> 3;        // 0..17
        int i0 = it * BM;
        int c0 = ct * BNc;
        int w = tid >> 6, L = tid & 63;
        int wr = w >> 1, wc = w & 1;  // wave -> 64x32 sub-tile
        const unsigned short* Ab = g_A + (size_t)b * Nn * Nn + (size_t)i0 * Nn;
        const float* Fb = fsrc + ((size_t)b * Cn + c0) * Nn;

#pragma unroll
        for (int u = 0; u < 4; u++) {
            int j = tid + u * 256;
            ics[j] = g_ics[b * Nn + j];
        }
        __syncthreads();

        // B staging state (T14 split: load-early into regs, scale+write late).
        int chunkB = tid;                 // 0..255
        int rrB = chunkB >> 2;            // c-row 0..63
        int gqB = (chunkB & 3) ^ ((rrB >> 1) & 3);
        const float* gB = Fb + (size_t)rrB * Nn + gqB * 8;
        float4 bv0, bv1;
        auto loadB = [&](int kt) {
            bv0 = *(const float4*)(gB + kt);
            bv1 = *(const float4*)(gB + kt + 4);
        };
        auto writeB = [&](int p, int kt) {
            const float* icp = &ics[kt + gqB * 8];
            ushort4 u0, u1;
            u0.x = f2bf(bv0.x * icp[0]);
            u0.y = f2bf(bv0.y * icp[1]);
            u0.z = f2bf(bv0.z * icp[2]);
            u0.w = f2bf(bv0.w * icp[3]);
            u1.x = f2bf(bv1.x * icp[4]);
            u1.y = f2bf(bv1.y * icp[5]);
            u1.z = f2bf(bv1.z * icp[6]);
            u1.w = f2bf(bv1.w * icp[7]);
            *(ushort4*)(Bs0 + p * 2048 + chunkB * 8) = u0;
            *(ushort4*)(Bs0 + p * 2048 + chunkB * 8 + 4) = u1;
        };
        auto stageA = [&](int p, int kt) {
#pragma unroll
            for (int h = 0; h < 2; h++) {
                int chunk = h * 256 + tid;               // 0..511
                int rr = chunk >> 2;                     // row 0..127
                int gq = (chunk & 3) ^ ((rr >> 1) & 3);  // swizzled k-quad
                const unsigned short* ga = Ab + (size_t)rr * Nn + kt + gq * 8;
                __builtin_amdgcn_global_load_lds(
                    (const __attribute__((address_space(1))) unsigned int*)ga,
                    (__attribute__((address_space(3))) unsigned int*)(As0 + p * 4096 + chunk * 8),
                    16, 0, 0);
            }
        };

        f32x4 acc[4][2] = {};
        int lrow = L & 15, quad = L >> 4;
        loadB(0);       // B loads issued first -> oldest in vmem queue
        stageA(0, 0);
        writeB(0, 0);   // prologue only: waits its own loads
        for (int kt = 0; kt < Nn; kt += BK) {
            int p = (kt >> 5) & 1;
            __syncthreads();  // buffer p ready (vmcnt+lgkm drained)
            if (kt + BK < Nn) {
                loadB(kt + BK);       // f32 B loads: latency hides under MFMAs
                stageA(1 - p, kt + BK);  // async LDS-DMA, in flight past barrier
            }
            short8 af[4], bf[2];
#pragma unroll
            for (int mt = 0; mt < 4; mt++) {
                int rr2 = wr * 64 + mt * 16 + lrow;
                int q = quad ^ ((rr2 >> 1) & 3);
                af[mt] = *(const short8*)(As0 + p * 4096 + rr2 * BK + q * 8);
            }
#pragma unroll
            for (int nt = 0; nt < 2; nt++) {
                int cc = wc * 32 + nt * 16 + lrow;
                int q = quad ^ ((cc >> 1) & 3);
                bf[nt] = *(const short8*)(Bs0 + p * 2048 + cc * BK + q * 8);
            }
#pragma unroll
            for (int mt = 0; mt < 4; mt++)
#pragma unroll
                for (int nt = 0; nt < 2; nt++)
                    acc[mt][nt] = __builtin_amdgcn_mfma_f32_16x16x32_bf16(af[mt], bf[nt],
                                                                          acc[mt][nt], 0, 0, 0);
            if (kt + BK < Nn) writeB(1 - p, kt + BK);  // waits B loads AFTER MFMAs
        }
        // Epilogue: D col=lane&15, row=(lane>>4)*4+reg  [m89-verified]
        int col = L & 15;
#pragma unroll
        for (int mt = 0; mt < 4; mt++)
#pragma unroll
            for (int rg = 0; rg < 4; rg++) {
                int i = i0 + wr * 64 + mt * 16 + quad * 4 + rg;
                float* orow = out + ((size_t)b * Nn + i) * Cn + c0 + wc * 32;
#pragma unroll
                for (int nt = 0; nt < 2; nt++) orow[nt * 16 + col] = acc[mt][nt][rg];
            }
    }
}

extern "C" void kernel_launch(void* const* d_in, const int* in_sizes, int n_in,
                              void* d_out, int out_size, void* d_ws, size_t ws_size,
                              hipStream_t stream) {
    (void)in_sizes; (void)n_in; (void)d_ws; (void)ws_size; (void)out_size;
    const float* f_src = (const float*)d_in[1];  // d_in[0] = f_tar unused by reference
    const float* K1 = (const float*)d_in[2];
    const float* K2 = (const float*)d_in[3];
    const float* R = (const float*)d_in[4];
    const float* t = (const float*)d_in[5];
    float* out = (float*)d_out;

    mega_kernel<<<dim3(GRID), dim3(256), 0, stream>>>(K1, K2, R, t, f_src, out);
}

// Round 4
// 190.553 us; speedup vs baseline: 2.8008x; 2.8008x over previous
//
#include <hip/hip_runtime.h>
#include <hip/hip_bf16.h>
#include <math.h>

#define Bn 8
#define Cn 1152
#define Nn 1024  // H*W

typedef short short8 __attribute__((ext_vector_type(8)));
typedef float f32x4 __attribute__((ext_vector_type(4)));

// Intermediates. Fully overwritten every call (poison-safe).
__device__ float g_csum_part[Bn * 32 * Nn];  // per-(b, seg) partial column sums
__device__ float g_icsum[Bn * Nn];           // 1/colsum
__device__ unsigned short g_A[(size_t)Bn * Nn * Nn];  // E[b][i][j] bf16 (unnormalized)

__device__ inline unsigned short f2bf(float x) {
    __hip_bfloat16 h = __float2bfloat16(x);
    unsigned short u;
    __builtin_memcpy(&u, &h, 2);
    return u;
}

__device__ inline void inv3(const float* M, float* o) {
    float a = M[0], b = M[1], c = M[2];
    float d = M[3], e = M[4], f = M[5];
    float g = M[6], h = M[7], i = M[8];
    float A0 = (e * i - f * h);
    float A1 = -(d * i - f * g);
    float A2 = (d * h - e * g);
    float det = a * A0 + b * A1 + c * A2;
    float inv = 1.0f / det;
    o[0] = A0 * inv;
    o[1] = -(b * i - c * h) * inv;
    o[2] = (b * f - c * e) * inv;
    o[3] = A1 * inv;
    o[4] = (a * i - c * g) * inv;
    o[5] = -(a * f - c * d) * inv;
    o[6] = A2 * inv;
    o[7] = -(a * h - b * g) * inv;
    o[8] = (a * e - b * d) * inv;
}

__device__ inline void mm3(const float* X, const float* Y, float* Z) {
    for (int r = 0; r < 3; r++)
        for (int c = 0; c < 3; c++)
            Z[r * 3 + c] = X[r * 3 + 0] * Y[0 * 3 + c] + X[r * 3 + 1] * Y[1 * 3 + c] +
                           X[r * 3 + 2] * Y[2 * 3 + c];
}

// F = inv(K2^T) skew(t) R inv(K1). SVD in the reference is a rank-2 no-op
// (skew(t)@R already has singular values (|t|,|t|,0)). Thread 0 per block.
__device__ inline void computeF(const float* K1, const float* K2, const float* R,
                                const float* t, int b, float* F) {
    float t0 = t[b * 3 + 0], t1 = t[b * 3 + 1], t2 = t[b * 3 + 2];
    float S[9] = {0.0f, -t2, t1, t2, 0.0f, -t0, -t1, t0, 0.0f};
    float E[9];
    mm3(S, &R[b * 9], E);
    float iK1[9], iK2[9];
    inv3(&K1[b * 9], iK1);
    inv3(&K2[b * 9], iK2);
    float iK2T[9] = {iK2[0], iK2[3], iK2[6], iK2[1], iK2[4], iK2[7], iK2[2], iK2[5], iK2[8]};
    float T[9];
    mm3(iK2T, E, T);
    mm3(T, iK1, F);
}

// Per-j coefficients: z_ij = |ix*P + iy*Q - R| - 0.5  (== 5*(d_epi - 0.1))
__device__ inline float4 zcoef(const float* F, int j) {
    float jx = (float)(j >> 5);
    float jy = (float)(j & 31);
    float l0 = F[0] * jx + F[1] * jy + F[2];
    float l1 = F[3] * jx + F[4] * jy + F[5];
    float l2 = F[6] * jx + F[7] * jy + F[8];
    l0 = l0 / l2;
    l1 = l1 / l2;
    float y0 = -1.0f / l1;
    float y1 = -(1.0f + l0 * 32.0f) / l1;
    float dy = y0 - y1;
    float invn = 1.0f / sqrtf(1024.0f + dy * dy);
    return make_float4(5.0f * dy * invn, 160.0f * invn, 160.0f * y0 * invn, 0.0f);
}

// Fused prep: per (b, seg) block of 32 rows, compute z once per (i,j), do the
// row softmax in-wave (full row per wave, lane owns j = lane+64k), emit
// E = exp(1 - rowsoftmax) as bf16 + per-(b,seg) partial column sums.
// Grid 256: lin&7 = b = XCD.  [round-1 version, verified twice]
__launch_bounds__(256) __global__ void fusedE_kernel(const float* __restrict__ K1,
                                                     const float* __restrict__ K2,
                                                     const float* __restrict__ R,
                                                     const float* __restrict__ t) {
    __shared__ float Fs[9];
    __shared__ float4 prm[Nn];        // 16 KB
    __shared__ float red[4][16][64];  // 16 KB, per-wave csum partials
    int lin = blockIdx.x;
    int b = lin & 7;
    int seg = lin >> 3;  // 0..31
    if (threadIdx.x == 0) computeF(K1, K2, R, t, b, Fs);
    __syncthreads();
#pragma unroll
    for (int u = 0; u < 4; u++) {
        int j = threadIdx.x * 4 + u;
        prm[j] = zcoef(Fs, j);
    }
    __syncthreads();
    int wv = threadIdx.x >> 6;
    int lane = threadIdx.x & 63;
    float px[16], py[16], pz[16];
#pragma unroll
    for (int k = 0; k < 16; k++) {
        float4 p = prm[lane + k * 64];
        px[k] = p.x;
        py[k] = p.y;
        pz[k] = p.z;
    }
    float csum[16];
#pragma unroll
    for (int k = 0; k < 16; k++) csum[k] = 0.0f;
#pragma unroll
    for (int rr = 0; rr < 8; rr++) {
        int i = seg * 32 + wv * 8 + rr;
        float ix = (float)(i >> 5), iy = (float)(i & 31);
        float e[16], m = -INFINITY;
#pragma unroll
        for (int k = 0; k < 16; k++) {
            e[k] = fabsf(fmaf(ix, px[k], fmaf(iy, py[k], -pz[k]))) - 0.5f;
            m = fmaxf(m, e[k]);
        }
#pragma unroll
        for (int o = 32; o > 0; o >>= 1) m = fmaxf(m, __shfl_xor(m, o, 64));
        float s = 0.0f;
#pragma unroll
        for (int k = 0; k < 16; k++) {
            e[k] = __expf(e[k] - m);  // reused below
            s += e[k];
        }
#pragma unroll
        for (int o = 32; o > 0; o >>= 1) s += __shfl_xor(s, o, 64);
        float rsi = 1.0f / s;
        unsigned short* arow = g_A + (size_t)(b * Nn + i) * Nn;
#pragma unroll
        for (int k = 0; k < 16; k++) {
            float E = __expf(1.0f - e[k] * rsi);
            csum[k] += E;
            arow[lane + k * 64] = f2bf(E);
        }
    }
#pragma unroll
    for (int k = 0; k < 16; k++) red[wv][k][lane] = csum[k];
    __syncthreads();
    int l2 = threadIdx.x & 63;
    int k0 = (threadIdx.x >> 6) * 4;
#pragma unroll
    for (int q = 0; q < 4; q++) {
        int k = k0 + q;
        float ssum = red[0][k][l2] + red[1][k][l2] + red[2][k][l2] + red[3][k][l2];
        g_csum_part[(b * 32 + seg) * Nn + k * 64 + l2] = ssum;
    }
}

// Finalize 1/colsum. Grid 8 (one per batch). Same accumulation order as the
// round-1 convert kernel -> bit-identical results.  [round-2 version, verified]
__global__ void icsum_kernel() {
    int b = blockIdx.x;
    int j0 = threadIdx.x * 4;
    float4 cs = *(const float4*)&g_csum_part[(b * 32 + 0) * Nn + j0];
#pragma unroll
    for (int it = 1; it < 32; it++) {
        float4 p = *(const float4*)&g_csum_part[(b * 32 + it) * Nn + j0];
        cs.x += p.x; cs.y += p.y; cs.z += p.z; cs.w += p.w;
    }
    float4 inv = make_float4(1.0f / cs.x, 1.0f / cs.y, 1.0f / cs.z, 1.0f / cs.w);
    *(float4*)&g_icsum[b * Nn + j0] = inv;
}

// out[b,i,c] = sum_j E[b,i,j] * (f_src[b,c,j]/csum[b,j]).
// 1/csum scale + f32->bf16 fold into B staging, T14-split: B f32 loads issue
// right after the barrier (oldest in vmem queue), A stages via async
// global_load_lds, MFMAs run, THEN the vmcnt wait + scale + ds_write for the
// next buffer. The B-load latency hides under this iteration's MFMAs instead
// of stalling them (round-2 write-early variant stalled: 79 us).
// 128(i) x 64(c) tile, 256 thr / 4 waves, 28 KB LDS -> 4-5 blocks/CU
// (~18 waves/CU). launch_bounds(256,4): 128-VGPR budget, no spill (round-3's
// (256,5) squeeze is the prime suspect for its 455 us collapse).
#define BM 128
#define BNc 64
#define BK 32

__launch_bounds__(256, 4) __global__ void gemm_kernel(const float* __restrict__ fsrc,
                                                      float* __restrict__ out) {
    __shared__ unsigned short As[2][BM * BK];   // 8 KB each
    __shared__ unsigned short Bs[2][BNc * BK];  // 4 KB each
    __shared__ float ics[Nn];                   // 4 KB
    int lin = blockIdx.x;
    int b = lin & 7;
    int s = lin >> 3;  // 0..143
    int it = s & 7;
    int ct = s >> 3;   // 0..17
    int i0 = it * BM;
    int c0 = ct * BNc;
    int t = threadIdx.x;
    int w = t >> 6, L = t & 63;
    int wr = w >> 1, wc = w & 1;  // wave -> 64x32 sub-tile
    const unsigned short* Ab = g_A + (size_t)b * Nn * Nn + (size_t)i0 * Nn;
    const float* Fb = fsrc + ((size_t)b * Cn + c0) * Nn;

#pragma unroll
    for (int u = 0; u < 4; u++) {
        int j = t + u * 256;
        ics[j] = g_icsum[b * Nn + j];
    }

    // B staging state (T14 split: load-early into regs, scale+write late).
    int chunkB = t;            // 0..255
    int rrB = chunkB >> 2;     // c-row 0..63
    int gqB = (chunkB & 3) ^ ((rrB >> 1) & 3);
    const float* gB = Fb + (size_t)rrB * Nn + gqB * 8;
    float4 bv0, bv1;
    auto loadB = [&](int kt) {
        bv0 = *(const float4*)(gB + kt);
        bv1 = *(const float4*)(gB + kt + 4);
    };
    auto writeB = [&](int p, int kt) {
        const float* icp = &ics[kt + gqB * 8];
        ushort4 u0, u1;
        u0.x = f2bf(bv0.x * icp[0]);
        u0.y = f2bf(bv0.y * icp[1]);
        u0.z = f2bf(bv0.z * icp[2]);
        u0.w = f2bf(bv0.w * icp[3]);
        u1.x = f2bf(bv1.x * icp[4]);
        u1.y = f2bf(bv1.y * icp[5]);
        u1.z = f2bf(bv1.z * icp[6]);
        u1.w = f2bf(bv1.w * icp[7]);
        *(ushort4*)(Bs[p] + chunkB * 8) = u0;
        *(ushort4*)(Bs[p] + chunkB * 8 + 4) = u1;
    };
    auto stageA = [&](int p, int kt) {
#pragma unroll
        for (int h = 0; h < 2; h++) {
            int chunk = h * 256 + t;                 // 0..511
            int rr = chunk >> 2;                     // row 0..127
            int gq = (chunk & 3) ^ ((rr >> 1) & 3);  // swizzled k-quad
            const unsigned short* ga = Ab + (size_t)rr * Nn + kt + gq * 8;
            __builtin_amdgcn_global_load_lds(
                (const __attribute__((address_space(1))) unsigned int*)ga,
                (__attribute__((address_space(3))) unsigned int*)(As[p] + chunk * 8), 16, 0, 0);
        }
    };

    f32x4 acc[4][2] = {};
    int lrow = L & 15, quad = L >> 4;
    __syncthreads();  // ics visible before first writeB
    loadB(0);         // B loads first -> oldest in vmem queue
    stageA(0, 0);
    writeB(0, 0);     // prologue: waits only its own 2 loads (vmcnt(2))
    for (int kt = 0; kt < Nn; kt += BK) {
        int p = (kt >> 5) & 1;
        __syncthreads();  // buffer p ready (vmcnt+lgkm drained)
        if (kt + BK < Nn) {
            loadB(kt + BK);          // f32 B loads: latency hides under MFMAs
            stageA(1 - p, kt + BK);  // async LDS-DMA, in flight past barrier
        }
        short8 af[4], bf[2];
#pragma unroll
        for (int mt = 0; mt < 4; mt++) {
            int rr2 = wr * 64 + mt * 16 + lrow;
            int q = quad ^ ((rr2 >> 1) & 3);
            af[mt] = *(const short8*)(As[p] + rr2 * BK + q * 8);
        }
#pragma unroll
        for (int nt = 0; nt < 2; nt++) {
            int cc = wc * 32 + nt * 16 + lrow;
            int q = quad ^ ((cc >> 1) & 3);
            bf[nt] = *(const short8*)(Bs[p] + cc * BK + q * 8);
        }
#pragma unroll
        for (int mt = 0; mt < 4; mt++)
#pragma unroll
            for (int nt = 0; nt < 2; nt++)
                acc[mt][nt] =
                    __builtin_amdgcn_mfma_f32_16x16x32_bf16(af[mt], bf[nt], acc[mt][nt], 0, 0, 0);
        if (kt + BK < Nn) writeB(1 - p, kt + BK);  // vmcnt wait lands AFTER MFMAs
    }
    // Epilogue: D col=lane&15, row=(lane>>4)*4+reg  [m89-verified]
    int col = L & 15;
#pragma unroll
    for (int mt = 0; mt < 4; mt++)
#pragma unroll
        for (int rg = 0; rg < 4; rg++) {
            int i = i0 + wr * 64 + mt * 16 + quad * 4 + rg;
            float* orow = out + ((size_t)b * Nn + i) * Cn + c0 + wc * 32;
#pragma unroll
            for (int nt = 0; nt < 2; nt++) orow[nt * 16 + col] = acc[mt][nt][rg];
        }
}

extern "C" void kernel_launch(void* const* d_in, const int* in_sizes, int n_in,
                              void* d_out, int out_size, void* d_ws, size_t ws_size,
                              hipStream_t stream) {
    (void)in_sizes; (void)n_in; (void)d_ws; (void)ws_size; (void)out_size;
    const float* f_src = (const float*)d_in[1];  // d_in[0] = f_tar unused by reference
    const float* K1 = (const float*)d_in[2];
    const float* K2 = (const float*)d_in[3];
    const float* R = (const float*)d_in[4];
    const float* t = (const float*)d_in[5];
    float* out = (float*)d_out;

    fusedE_kernel<<<dim3(256), dim3(256), 0, stream>>>(K1, K2, R, t);
    icsum_kernel<<<dim3(8), dim3(256), 0, stream>>>();
    gemm_kernel<<<dim3(Bn * (Nn / BM) * (Cn / BNc)), dim3(256), 0, stream>>>(f_src, out);
}